// Round 3
// baseline (600.492 us; speedup 1.0000x reference)
//
#include <hip/hip_runtime.h>

#define BB   16
#define CC   32
#define HH   384
#define WW   384
#define HW   (HH * WW)        // 147456
#define HID  128
#define KOUT 288              // NK*K*K = 32*9
#define NPLANE (BB * CC)      // 512

// batch chunking for L3 producer->consumer reuse:
// 8 samples * 32 ch * 147456 px * 4 B = 151 MB per chunk < 256 MB L3.
#define SAMPLES_PER_CHUNK 8
#define NCHUNK (BB / SAMPLES_PER_CHUNK)            // 2
#define PLANES_PER_CHUNK (SAMPLES_PER_CHUNK * CC)  // 256

// conv geometry: each thread = 4 cols (one float4) x 24 rows
#define CG_PER_ROW 96                              // 384/4 col-groups
#define ROWS_PER_THREAD 24
#define NBANDS (HH / ROWS_PER_THREAD)              // 16
#define THREADS_PER_PLANE (CG_PER_ROW * NBANDS)    // 1536
#define BLOCKS_PER_PLANE (THREADS_PER_PLANE / 256) // 6

typedef float f4 __attribute__((ext_vector_type(4)));

// ---------------------------------------------------------------------------
// 1) Global average pool over one chunk of planes. Normal (cache-filling)
//    loads on purpose: the whole point is to leave this chunk of x resident
//    in L3 for the conv launch that immediately follows on the stream.
// ---------------------------------------------------------------------------
__global__ __launch_bounds__(1024) void pool_kernel(const float* __restrict__ x,
                                                    float* __restrict__ pooled,
                                                    int plane_base) {
    const int bc = plane_base + blockIdx.x;
    const f4* pv = (const f4*)(x + (size_t)bc * HW);
    float s = 0.f;
    for (int i = threadIdx.x; i < HW / 4; i += 1024) {
        f4 v = pv[i];
        s += (v.x + v.y) + (v.z + v.w);
    }
#pragma unroll
    for (int off = 32; off; off >>= 1) s += __shfl_down(s, off);
    __shared__ float red[16];
    if ((threadIdx.x & 63) == 0) red[threadIdx.x >> 6] = s;
    __syncthreads();
    if (threadIdx.x == 0) {
        float t = 0.f;
#pragma unroll
        for (int wv = 0; wv < 16; ++wv) t += red[wv];
        pooled[bc] = t * (1.0f / (float)HW);
    }
}

// ---------------------------------------------------------------------------
// 2) MLP kernel generator for one chunk of samples. fp32, tiny.
// ---------------------------------------------------------------------------
__global__ __launch_bounds__(128) void mlp_kernel(const float* __restrict__ pooled,
                                                  const float* __restrict__ w1,
                                                  const float* __restrict__ b1,
                                                  const float* __restrict__ w2,
                                                  const float* __restrict__ b2,
                                                  float* __restrict__ kern,
                                                  int sample_base) {
    const int b   = sample_base + blockIdx.x;
    const int tid = threadIdx.x;
    __shared__ float pc[CC];
    __shared__ float hdn[HID];
    if (tid < CC) pc[tid] = pooled[b * CC + tid];
    __syncthreads();

    float a = b1[tid];
#pragma unroll
    for (int c = 0; c < CC; ++c) a += pc[c] * w1[c * HID + tid];
    hdn[tid] = fmaxf(a, 0.f);
    __syncthreads();

    for (int o = tid; o < KOUT; o += 128) {
        float a2 = b2[o];
#pragma unroll 8
        for (int j = 0; j < HID; ++j) a2 += hdn[j] * w2[j * KOUT + o];
        kern[b * KOUT + o] = a2;
    }
}

// ---------------------------------------------------------------------------
// 3) Depthwise 3x3 conv for one chunk of planes — register sliding window.
//    Reads are L3 hits (pool of the same chunk just streamed them in).
//    NT stores keep the 302 MB out-stream from evicting the chunk's x data.
// ---------------------------------------------------------------------------
__device__ __forceinline__ void load_row6(const float* __restrict__ xp,
                                          int r, int c0, int cg, float* a) {
    if ((unsigned)r < (unsigned)HH) {
        const float* p = xp + r * WW + c0;
        const f4 v = *reinterpret_cast<const f4*>(p);
        a[0] = (cg > 0)              ? p[-1] : 0.f;   // left halo (same cache line)
        a[1] = v.x; a[2] = v.y; a[3] = v.z; a[4] = v.w;
        a[5] = (cg < CG_PER_ROW - 1) ? p[4]  : 0.f;   // right halo (same cache line)
    } else {
        a[0] = a[1] = a[2] = a[3] = a[4] = a[5] = 0.f;
    }
}

__global__ __launch_bounds__(256) void conv_kernel(const float* __restrict__ x,
                                                   const float* __restrict__ kern,
                                                   float* __restrict__ out,
                                                   int plane_base) {
    const int plane = plane_base + (int)(blockIdx.x / BLOCKS_PER_PLANE);
    const int rem   = (blockIdx.x % BLOCKS_PER_PLANE) * 256 + (int)threadIdx.x;
    const int band  = rem / CG_PER_ROW;
    const int cg    = rem - band * CG_PER_ROW;
    const int c0    = cg * 4;

    const float* xp = x   + (size_t)plane * HW;
    float*       op = out + (size_t)plane * HW;

    float w[9];
    const float* kw = kern + plane * 9;          // block-uniform -> scalar loads
#pragma unroll
    for (int t = 0; t < 9; ++t) w[t] = kw[t];

    const int r0 = band * ROWS_PER_THREAD;
    float aT[6], aM[6], aB[6];
    float aN[6] = {0.f, 0.f, 0.f, 0.f, 0.f, 0.f};
    load_row6(xp, r0 - 1, c0, cg, aT);
    load_row6(xp, r0,     c0, cg, aM);
    load_row6(xp, r0 + 1, c0, cg, aB);

#pragma unroll
    for (int i = 0; i < ROWS_PER_THREAD; ++i) {
        const int r = r0 + i;
        if (i < ROWS_PER_THREAD - 1)              // one-row lookahead prefetch
            load_row6(xp, r + 2, c0, cg, aN);

        f4 o;
        o.x = w[0]*aT[0] + w[1]*aT[1] + w[2]*aT[2]
            + w[3]*aM[0] + w[4]*aM[1] + w[5]*aM[2]
            + w[6]*aB[0] + w[7]*aB[1] + w[8]*aB[2];
        o.y = w[0]*aT[1] + w[1]*aT[2] + w[2]*aT[3]
            + w[3]*aM[1] + w[4]*aM[2] + w[5]*aM[3]
            + w[6]*aB[1] + w[7]*aB[2] + w[8]*aB[3];
        o.z = w[0]*aT[2] + w[1]*aT[3] + w[2]*aT[4]
            + w[3]*aM[2] + w[4]*aM[3] + w[5]*aM[4]
            + w[6]*aB[2] + w[7]*aB[3] + w[8]*aB[4];
        o.w = w[0]*aT[3] + w[1]*aT[4] + w[2]*aT[5]
            + w[3]*aM[3] + w[4]*aM[4] + w[5]*aM[5]
            + w[6]*aB[3] + w[7]*aB[4] + w[8]*aB[5];

        __builtin_nontemporal_store(o, reinterpret_cast<f4*>(op + (size_t)r * WW + c0));

#pragma unroll
        for (int t = 0; t < 6; ++t) { aT[t] = aM[t]; aM[t] = aB[t]; aB[t] = aN[t]; }
    }
}

// ---------------------------------------------------------------------------
extern "C" void kernel_launch(void* const* d_in, const int* in_sizes, int n_in,
                              void* d_out, int out_size, void* d_ws, size_t ws_size,
                              hipStream_t stream) {
    const float* x  = (const float*)d_in[0];
    const float* w1 = (const float*)d_in[1];
    const float* b1 = (const float*)d_in[2];
    const float* w2 = (const float*)d_in[3];
    const float* b2 = (const float*)d_in[4];
    float* out = (float*)d_out;

    float* pooled = (float*)d_ws;        // 512 floats
    float* kern   = pooled + BB * CC;    // 16*288 = 4608 floats

    // chunked pipeline: pool(chunk) -> mlp(chunk) -> conv(chunk).
    // stream ordering = free producer->consumer barrier; each chunk's x-data
    // (151 MB) is L3-resident when its conv launch starts.
    for (int ch = 0; ch < NCHUNK; ++ch) {
        const int pbase = ch * PLANES_PER_CHUNK;
        const int sbase = ch * SAMPLES_PER_CHUNK;
        pool_kernel<<<PLANES_PER_CHUNK, 1024, 0, stream>>>(x, pooled, pbase);
        mlp_kernel<<<SAMPLES_PER_CHUNK, 128, 0, stream>>>(pooled, w1, b1, w2, b2, kern, sbase);
        conv_kernel<<<PLANES_PER_CHUNK * BLOCKS_PER_PLANE, 256, 0, stream>>>(x, kern, out, pbase);
    }
}

// Round 5
// 577.283 us; speedup vs baseline: 1.0402x; 1.0402x over previous
//
#include <hip/hip_runtime.h>

#define BB   16
#define CC   32
#define HH   384
#define WW   384
#define HW   (HH * WW)        // 147456
#define HID  128
#define KOUT 288              // NK*K*K = 32*9
#define NPLANE (BB * CC)      // 512

// batch chunking: 4 samples * 32 ch * 147456 px * 4 B = 75.5 MB per chunk.
// Two chunks co-resident in the 256 MB L3 (151 MB) -> the chunk conv reads
// was JUST streamed in by its pool and cannot have been evicted by the next
// chunk yet (conv NT-stores bypass the cache).
#define SAMPLES_PER_CHUNK 4
#define NCHUNK (BB / SAMPLES_PER_CHUNK)            // 4
#define PLANES_PER_CHUNK (SAMPLES_PER_CHUNK * CC)  // 128

// conv geometry: each thread = 4 cols (one float4) x 24 rows
#define CG_PER_ROW 96                              // 384/4 col-groups
#define ROWS_PER_THREAD 24
#define NBANDS (HH / ROWS_PER_THREAD)              // 16
#define THREADS_PER_PLANE (CG_PER_ROW * NBANDS)    // 1536
#define BLOCKS_PER_PLANE (THREADS_PER_PLANE / 256) // 6

typedef float f4 __attribute__((ext_vector_type(4)));

// ---------------------------------------------------------------------------
// 1) Global average pool over one chunk of planes. Normal (cache-filling)
//    loads: leaves this chunk of x resident in L3 for the conv that follows.
// ---------------------------------------------------------------------------
__global__ __launch_bounds__(1024) void pool_kernel(const float* __restrict__ x,
                                                    float* __restrict__ pooled,
                                                    int plane_base) {
    const int bc = plane_base + blockIdx.x;
    const f4* pv = (const f4*)(x + (size_t)bc * HW);
    float s = 0.f;
    for (int i = threadIdx.x; i < HW / 4; i += 1024) {
        f4 v = pv[i];
        s += (v.x + v.y) + (v.z + v.w);
    }
#pragma unroll
    for (int off = 32; off; off >>= 1) s += __shfl_down(s, off);
    __shared__ float red[16];
    if ((threadIdx.x & 63) == 0) red[threadIdx.x >> 6] = s;
    __syncthreads();
    if (threadIdx.x == 0) {
        float t = 0.f;
#pragma unroll
        for (int wv = 0; wv < 16; ++wv) t += red[wv];
        pooled[bc] = t * (1.0f / (float)HW);
    }
}

// ---------------------------------------------------------------------------
// 2) Depthwise 3x3 conv with the MLP folded into the block prologue.
//    Each block needs only the 9 weights of ITS plane:
//      hdn = relu(b1 + pooled[b,:] @ w1)          (128 threads, 32 MAD each)
//      w[t] = b2[c*9+t] + hdn @ w2[:, c*9+t]      (144 threads: 9 outs x 16)
//    The first 3 x-row loads are issued BEFORE the prologue so HBM latency
//    hides under it. Main loop: register sliding window, float4 in / NT out.
// ---------------------------------------------------------------------------
__device__ __forceinline__ void load_row6(const float* __restrict__ xp,
                                          int r, int c0, int cg, float* a) {
    if ((unsigned)r < (unsigned)HH) {
        const float* p = xp + r * WW + c0;
        const f4 v = *reinterpret_cast<const f4*>(p);
        a[0] = (cg > 0)              ? p[-1] : 0.f;   // left halo (same cache line)
        a[1] = v.x; a[2] = v.y; a[3] = v.z; a[4] = v.w;
        a[5] = (cg < CG_PER_ROW - 1) ? p[4]  : 0.f;   // right halo (same cache line)
    } else {
        a[0] = a[1] = a[2] = a[3] = a[4] = a[5] = 0.f;
    }
}

__global__ __launch_bounds__(256) void conv_kernel(const float* __restrict__ x,
                                                   const float* __restrict__ pooled,
                                                   const float* __restrict__ w1,
                                                   const float* __restrict__ b1,
                                                   const float* __restrict__ w2,
                                                   const float* __restrict__ b2,
                                                   float* __restrict__ out,
                                                   int plane_base) {
    const int plane = plane_base + (int)(blockIdx.x / BLOCKS_PER_PLANE);
    const int bs    = plane >> 5;                // sample index (CC == 32)
    const int chn   = plane & 31;                // channel index
    const int rem   = (blockIdx.x % BLOCKS_PER_PLANE) * 256 + (int)threadIdx.x;
    const int band  = rem / CG_PER_ROW;
    const int cg    = rem - band * CG_PER_ROW;
    const int c0    = cg * 4;
    const int tid   = threadIdx.x;

    const float* xp = x   + (size_t)plane * HW;
    float*       op = out + (size_t)plane * HW;
    const int r0 = band * ROWS_PER_THREAD;

    // issue first three row loads early — HBM latency hides under the MLP
    float aT[6], aM[6], aB[6];
    load_row6(xp, r0 - 1, c0, cg, aT);
    load_row6(xp, r0,     c0, cg, aM);
    load_row6(xp, r0 + 1, c0, cg, aB);

    // ---- inline MLP (this plane's 9 weights only) ----
    __shared__ float pc_s[CC];
    __shared__ float hdn_s[HID];
    __shared__ float wsh[9];
    if (tid < CC) pc_s[tid] = pooled[bs * CC + tid];
    __syncthreads();
    if (tid < HID) {
        float a = b1[tid];
#pragma unroll
        for (int c = 0; c < CC; ++c) a += pc_s[c] * w1[c * HID + tid];
        hdn_s[tid] = fmaxf(a, 0.f);
    }
    __syncthreads();
    if (tid < 144) {                       // 9 outputs x 16 lanes
        const int o  = tid >> 4;
        const int j0 = (tid & 15) * 8;
        const int oc = chn * 9 + o;
        float a2 = 0.f;
#pragma unroll
        for (int j = 0; j < 8; ++j) a2 += hdn_s[j0 + j] * w2[(j0 + j) * KOUT + oc];
        a2 += __shfl_down(a2, 8);          // 16-lane group reduce (junk from
        a2 += __shfl_down(a2, 4);          // out-of-group lanes never reaches
        a2 += __shfl_down(a2, 2);          // lane 0 of each group)
        a2 += __shfl_down(a2, 1);
        if ((tid & 15) == 0) wsh[o] = a2 + b2[oc];
    }
    __syncthreads();
    float w[9];
#pragma unroll
    for (int t = 0; t < 9; ++t) w[t] = wsh[t];

    // ---- main loop: register sliding window ----
    float aN[6] = {0.f, 0.f, 0.f, 0.f, 0.f, 0.f};
#pragma unroll
    for (int i = 0; i < ROWS_PER_THREAD; ++i) {
        const int r = r0 + i;
        if (i < ROWS_PER_THREAD - 1)              // one-row lookahead prefetch
            load_row6(xp, r + 2, c0, cg, aN);

        f4 o;
        o.x = w[0]*aT[0] + w[1]*aT[1] + w[2]*aT[2]
            + w[3]*aM[0] + w[4]*aM[1] + w[5]*aM[2]
            + w[6]*aB[0] + w[7]*aB[1] + w[8]*aB[2];
        o.y = w[0]*aT[1] + w[1]*aT[2] + w[2]*aT[3]
            + w[3]*aM[1] + w[4]*aM[2] + w[5]*aM[3]
            + w[6]*aB[1] + w[7]*aB[2] + w[8]*aB[3];
        o.z = w[0]*aT[2] + w[1]*aT[3] + w[2]*aT[4]
            + w[3]*aM[2] + w[4]*aM[3] + w[5]*aM[4]
            + w[6]*aB[2] + w[7]*aB[3] + w[8]*aB[4];
        o.w = w[0]*aT[3] + w[1]*aT[4] + w[2]*aT[5]
            + w[3]*aM[3] + w[4]*aM[4] + w[5]*aM[5]
            + w[6]*aB[3] + w[7]*aB[4] + w[8]*aB[5];

        __builtin_nontemporal_store(o, reinterpret_cast<f4*>(op + (size_t)r * WW + c0));

#pragma unroll
        for (int t = 0; t < 6; ++t) { aT[t] = aM[t]; aM[t] = aB[t]; aB[t] = aN[t]; }
    }
}

// ---------------------------------------------------------------------------
extern "C" void kernel_launch(void* const* d_in, const int* in_sizes, int n_in,
                              void* d_out, int out_size, void* d_ws, size_t ws_size,
                              hipStream_t stream) {
    const float* x  = (const float*)d_in[0];
    const float* w1 = (const float*)d_in[1];
    const float* b1 = (const float*)d_in[2];
    const float* w2 = (const float*)d_in[3];
    const float* b2 = (const float*)d_in[4];
    float* out = (float*)d_out;

    float* pooled = (float*)d_ws;        // 512 floats

    // chunked pipeline: pool(chunk) -> conv(chunk). 75 MB chunks so two
    // chunks co-reside in the 256 MB L3; stream order = free barrier.
    for (int ch = 0; ch < NCHUNK; ++ch) {
        const int pbase = ch * PLANES_PER_CHUNK;
        pool_kernel<<<PLANES_PER_CHUNK, 1024, 0, stream>>>(x, pooled, pbase);
        conv_kernel<<<PLANES_PER_CHUNK * BLOCKS_PER_PLANE, 256, 0, stream>>>(
            x, pooled, w1, b1, w2, b2, out, pbase);
    }
}